// Round 11
// baseline (8332.368 us; speedup 1.0000x reference)
//
#include <hip/hip_runtime.h>
#include <hip/hip_bf16.h>
#include <stdint.h>

typedef unsigned short u16;
typedef uint32_t u32;
typedef unsigned long long u64;
typedef float f32x4 __attribute__((ext_vector_type(4)));
typedef __bf16 bf16x8 __attribute__((ext_vector_type(8)));

__device__ inline u16 f2bf(float f) {
  __bf16 h = (__bf16)f;                 // RTNE
  return __builtin_bit_cast(u16, h);
}
__device__ inline f32x4 mfma16(bf16x8 a, bf16x8 b, f32x4 c) {
  return __builtin_amdgcn_mfma_f32_16x16x32_bf16(a, b, c, 0, 0, 0);
}
// split 8 contiguous fp32 into bf16 hi + lo fragments (cached loads)
__device__ inline void cvt8(const float* p, bf16x8& h, bf16x8& l) {
  f32x4 u = *(const f32x4*)p;
  f32x4 v = *(const f32x4*)(p + 4);
#pragma unroll
  for (int i = 0; i < 4; ++i) {
    float a = u[i]; __bf16 ah = (__bf16)a; h[i] = ah; l[i] = (__bf16)(a - (float)ah);
    float b = v[i]; __bf16 bh = (__bf16)b; h[i + 4] = bh; l[i + 4] = (__bf16)(b - (float)bh);
  }
}
// gather 8 k-strided fp32 (stride 1024 floats) into bf16 hi + lo fragments
__device__ inline void gather8(const float* p, bf16x8& h, bf16x8& l) {
#pragma unroll
  for (int e = 0; e < 8; ++e) {
    float f = p[(size_t)e * 1024];
    __bf16 x = (__bf16)f;
    h[e] = x; l[e] = (__bf16)(f - (float)x);
  }
}

// ---- coherence-point (bypass) accessors ----
__device__ inline u64 ld64(const u64* p) {
  return __hip_atomic_load(p, __ATOMIC_RELAXED, __HIP_MEMORY_SCOPE_AGENT);
}
__device__ inline void st64(u64* p, u64 v) {
  __hip_atomic_store(p, v, __ATOMIC_RELAXED, __HIP_MEMORY_SCOPE_AGENT);
}

// Epoch-tagged state plane: u64 word = {epoch32 | bf16pair32}, layout
// word[(j>>1)*32 + b]  (j = H column, b = batch row). 128KB per plane.
// Combined poll: one lane issues all 32 tagged words of its 4 k-slice
// fragments; spin until every tag matches (the POLL IS THE LOAD).
struct W4 { u32 w[4]; };
__device__ inline bool try32(const u64* p, u32 tag, u64 q[32]) {
#pragma unroll
  for (int ks = 0; ks < 4; ++ks) {
#pragma unroll
    for (int p4 = 0; p4 < 4; ++p4) {
      q[ks * 8 + p4]     = ld64(p + ks * 512 + p4 * 32);
      q[ks * 8 + 4 + p4] = ld64(p + ks * 512 + p4 * 32 + 16);
    }
  }
  bool ok = true;
#pragma unroll
  for (int i = 0; i < 32; ++i) ok &= ((u32)(q[i] >> 32) == tag);
  return ok;
}
__device__ inline void poll32(const u64* p, u32 tag, u64 q[32]) {
  int it = 0;
  while (__ballot(try32(p, tag, q)) != ~0ull) {
    if (++it > 1000000) break;          // garbage > hang
    __builtin_amdgcn_s_sleep(4);
  }
}
__device__ inline bf16x8 lo4(const u64* q) {
  W4 a = {{(u32)q[0], (u32)q[1], (u32)q[2], (u32)q[3]}};
  return __builtin_bit_cast(bf16x8, a);
}

struct RecArgs {
  const float* x;
  const float *W_ix, *W_ih, *W_ic, *W_fx, *W_fh, *W_fc, *W_cx, *W_ch;
  const float *W_ox, *W_oh, *W_oc;
  const float *b_i, *b_f, *b_c, *b_o;
  u64 *hE, *cE;          // epoch-tagged state planes, 128KB each
  float* out;
};

// Persistent LSTM, barrier-free dataflow: 256 blocks x 512 threads (8 waves).
// Block owns 4 H-columns of each gate; wave w owns K-slice [w*128,(w+1)*128).
// Sync = epoch tags carried IN the state words (one visibility hop/phase).
// Arithmetic order is bit-identical to the round-9 kernel (absmax 0.017089).
__global__ __launch_bounds__(512, 1) void lstm_rec(RecArgs a) {
  __shared__ float scr[8 * 2 * 16 * 17];     // [wave][mt][row][col], padded

  const int tid = threadIdx.x;
  const int wg = blockIdx.x;
  const int j0 = wg * 4;
  const int lane = tid & 63;
  const int wave = tid >> 6;
  const int mrow = lane & 15;               // A-row (batch) lane index
  const int kgroup = lane >> 4;             // k sub-block 0..3
  const int kq = kgroup * 8;
  const int kw = wave * 128;                // per-wave K slice
  const int col = lane & 15;                // B/D column lane index
  const int rq = (lane >> 4) * 4;           // D row quad base
  // combined-poll base: word (j8=wave*16+kgroup, pair 0, row mrow)
  const int pbase = (wave * 16 + kgroup) * 128 + mrow;

  // ---- one-time: B-fragments (weights) -> registers, hi/lo split ----
  const int fjj = col >> 2, fg = col & 3;   // col = jj*4 + g
  const int fj = j0 + fjj;
  const float* Wx = (fg == 0) ? a.W_ix : (fg == 1) ? a.W_fx : (fg == 2) ? a.W_cx : a.W_ox;
  const float* Wh = (fg == 0) ? a.W_ih : (fg == 1) ? a.W_fh : (fg == 2) ? a.W_ch : a.W_oh;
  const float* Wc = (fg == 0) ? a.W_ic : (fg == 1) ? a.W_fc : (fg == 3) ? a.W_oc : a.W_ic;

  bf16x8 bxh[4], bxl[4], bhh[4], bhl[4], bch[4], bcl[4];
#pragma unroll
  for (int ks = 0; ks < 4; ++ks) {
    const size_t k8 = (size_t)(kw + ks * 32 + kq);
    gather8(Wx + k8 * 1024 + fj, bxh[ks], bxl[ks]);
    gather8(Wh + k8 * 1024 + fj, bhh[ks], bhl[ks]);
    if (fg != 2) {
      gather8(Wc + k8 * 1024 + fj, bch[ks], bcl[ks]);
    } else {
      bf16x8 z = {};
      bch[ks] = z; bcl[ks] = z;
    }
  }

  // elementwise thread constants (threads 0..127: b = tid>>2, jj = tid&3)
  const int eb = tid >> 2, ejj = tid & 3, ej = j0 + (tid & 3);
  const int widx = (ej >> 1) * 32 + eb;     // tagged-word index of own pair
  // ---- init own state words: {tag=0 | 0.0bf16 pair} ----
  if (tid < 128 && (tid & 1) == 0) {
    st64(a.hE + widx, 0ull);
    st64(a.cE + widx, 0ull);
  }
  float bi = 0.f, bfv = 0.f, bcv = 0.f, bo = 0.f;
  if (tid < 128) {
    bi = a.b_i[ej]; bfv = a.b_f[eb * 1024 + ej]; bcv = a.b_c[ej]; bo = a.b_o[ej];
  }

  float c_reg = 0.f, o_pre = 0.f;
  bf16x8 cf0[4] = {}, cf1[4] = {};          // carried c_{t-1} fragments

  for (int t = 0; t < 512; ++t) {
    // ======== phase 1: pre-gates = x@Wx + h@Wh + c_{t-1}@Wc ========
    // peephole chain first: separate accumulator (order-independent vs acc),
    // uses only carried regs -> fills part of the h-visibility window
    f32x4 pc0 = {}, pc1 = {};
#pragma unroll
    for (int ks = 0; ks < 4; ++ks) {
      pc0 = mfma16(cf0[ks], bch[ks], pc0);
      pc0 = mfma16(cf0[ks], bcl[ks], pc0);
      pc1 = mfma16(cf1[ks], bch[ks], pc1);
      pc1 = mfma16(cf1[ks], bcl[ks], pc1);
    }
    // combined poll of all 32 h_{t-1} tagged words (tag == t)
    u64 qh[32];
    poll32(a.hE + pbase, (u32)t, qh);
    // MFMA chain in EXACT round-9 order (per-ks x/h interleave)
    f32x4 acc0 = {}, acc1 = {};
#pragma unroll
    for (int ks = 0; ks < 4; ++ks) {
      const int ka = kw + ks * 32 + kq;
      bf16x8 ah0 = lo4(qh + ks * 8);
      bf16x8 ah1 = lo4(qh + ks * 8 + 4);
      bf16x8 xh0, xl0, xh1, xl1;
      const float* xp = a.x + ((size_t)(t * 32 + mrow) << 10) + ka;
      cvt8(xp, xh0, xl0);
      cvt8(xp + (16 << 10), xh1, xl1);
      acc0 = mfma16(xh0, bxh[ks], acc0);
      acc0 = mfma16(xl0, bxh[ks], acc0);
      acc0 = mfma16(xh0, bxl[ks], acc0);
      acc0 = mfma16(ah0, bhh[ks], acc0);
      acc0 = mfma16(ah0, bhl[ks], acc0);
      acc1 = mfma16(xh1, bxh[ks], acc1);
      acc1 = mfma16(xl1, bxh[ks], acc1);
      acc1 = mfma16(xh1, bxl[ks], acc1);
      acc1 = mfma16(ah1, bhh[ks], acc1);
      acc1 = mfma16(ah1, bhl[ks], acc1);
    }
    {
      const bool take_pc = (col & 3) != 3;   // o-gate peephole deferred
#pragma unroll
      for (int v = 0; v < 4; ++v) {
        scr[((wave * 2 + 0) * 16 + rq + v) * 17 + col] = acc0[v] + (take_pc ? pc0[v] : 0.f);
        scr[((wave * 2 + 1) * 16 + rq + v) * 17 + col] = acc1[v] + (take_pc ? pc1[v] : 0.f);
      }
    }
    __syncthreads();
    if (tid < 128) {
      float pre[4];
#pragma unroll
      for (int g = 0; g < 4; ++g) {
        float s = 0.f;
#pragma unroll
        for (int w = 0; w < 8; ++w)
          s += scr[((w * 2 + (eb >> 4)) * 16 + (eb & 15)) * 17 + ejj * 4 + g];
        pre[g] = s;
      }
      float iv = 1.f / (1.f + expf(-(pre[0] + bi)));
      float fv = 1.f / (1.f + expf(-(pre[1] + bfv)));
      float cv = tanhf(pre[2] + bcv);
      c_reg = fv * c_reg + iv * cv;           // fp32 carry, owner thread
      u32 cb = (u32)f2bf(c_reg);
      u32 cpart = __shfl_xor(cb, 1);
      if ((tid & 1) == 0)
        st64(a.cE + widx, ((u64)(u32)(t + 1) << 32) | (u64)(cb | (cpart << 16)));
      o_pre = pre[3] + bo;
    }
    __syncthreads();                          // keep waves phase-aligned

    // ======== phase 2: o-gate peephole = c_t @ W_oc ========
    u64 qc[32];
    poll32(a.cE + pbase, (u32)(t + 1), qc);
    f32x4 a20 = {}, a21 = {};
#pragma unroll
    for (int ks = 0; ks < 4; ++ks) {
      cf0[ks] = lo4(qc + ks * 8);             // save as carry for phase1(t+1)
      cf1[ks] = lo4(qc + ks * 8 + 4);
      a20 = mfma16(cf0[ks], bch[ks], a20);
      a20 = mfma16(cf0[ks], bcl[ks], a20);
      a21 = mfma16(cf1[ks], bch[ks], a21);
      a21 = mfma16(cf1[ks], bcl[ks], a21);
    }
#pragma unroll
    for (int v = 0; v < 4; ++v) {
      scr[((wave * 2 + 0) * 16 + rq + v) * 17 + col] = a20[v];
      scr[((wave * 2 + 1) * 16 + rq + v) * 17 + col] = a21[v];
    }
    __syncthreads();
    if (tid < 128) {
      float s = o_pre;
#pragma unroll
      for (int w = 0; w < 8; ++w)
        s += scr[((w * 2 + (eb >> 4)) * 16 + (eb & 15)) * 17 + ejj * 4 + 3];
      float ov = 1.f / (1.f + expf(-s));
      float hv = ov * tanhf(c_reg);
      u32 hb = (u32)f2bf(hv);
      u32 hpart = __shfl_xor(hb, 1);
      if ((tid & 1) == 0)
        st64(a.hE + widx, ((u64)(u32)(t + 1) << 32) | (u64)(hb | (hpart << 16)));
      if (t == 511) a.out[eb * 1024 + ej] = hv;
    }
    __syncthreads();
  }
}

extern "C" void kernel_launch(void* const* d_in, const int* in_sizes, int n_in,
                              void* d_out, int out_size, void* d_ws, size_t ws_size,
                              hipStream_t stream) {
  (void)in_sizes; (void)n_in; (void)out_size;
  RecArgs ra;
  ra.x    = (const float*)d_in[0];
  ra.W_ix = (const float*)d_in[1];
  ra.W_ih = (const float*)d_in[2];
  ra.W_ic = (const float*)d_in[3];
  ra.W_fx = (const float*)d_in[4];
  ra.W_fh = (const float*)d_in[5];
  ra.W_fc = (const float*)d_in[6];
  ra.W_cx = (const float*)d_in[7];
  ra.W_ch = (const float*)d_in[8];
  ra.W_ox = (const float*)d_in[9];
  ra.W_oh = (const float*)d_in[10];
  ra.W_oc = (const float*)d_in[11];
  ra.b_i  = (const float*)d_in[12];
  ra.b_f  = (const float*)d_in[13];
  ra.b_c  = (const float*)d_in[14];
  ra.b_o  = (const float*)d_in[15];

  char* ws = (char*)d_ws;
  size_t off = 0;
  auto alloc = [&](size_t bytes) {
    char* p = ws + off;
    off = (off + bytes + 255) & ~(size_t)255;
    return p;
  };
  ra.hE  = (u64*)alloc(16384 * 8);   // epoch-tagged h plane (128KB)
  ra.cE  = (u64*)alloc(16384 * 8);   // epoch-tagged c plane (128KB)
  ra.out = (float*)d_out;
  if (off > ws_size) return;         // visible failure if ws too small

  void* args[] = {&ra};
  hipError_t e = hipLaunchCooperativeKernel((void*)lstm_rec, dim3(256), dim3(512),
                                            args, 0, stream);
  if (e != hipSuccess) {
    // co-residency still holds: 1 block/CU x 256 blocks on 256 CUs
    lstm_rec<<<dim3(256), dim3(512), 0, stream>>>(ra);
  }
}